// Round 3
// baseline (479.891 us; speedup 1.0000x reference)
//
#include <hip/hip_runtime.h>
#include <hip/hip_bf16.h>
#include <stdint.h>

// ---------------------------------------------------------------------------
// LBConv: y = fc(relu(conv3x3_ternary(x))) + b
//   x        : [32][256][56][56] f32
//   binary_w : [512][256][3][3]  f32 (ternary)
//   fc_w     : [256][512]        f32
//   fc_b     : [256]             f32
//   out      : [32][256][56][56] f32
//
// R3 vs R2 (conv1 249us @ MfmaUtil 49%, Occ 22%, total 474us):
//  - BK=128 -> BK=64: 32KB LDS/block -> 5 blocks/CU (was 2). The barrier
//    drain (vmcnt(0)+s_barrier) now overlaps across 5 independent block
//    pipelines per CU. Mirrors m132's 3-vs-2-blocks 874-vs-508 TF result.
//  - Wp gains khalf axis; Y relayout [khalf2][r2][khi8][w64][klo8]; A2
//    re-keyed by kblk so every BK=64 K-tile is one contiguous 16KB chunk
//    (global_load_lds wave-uniform constraint).
// ---------------------------------------------------------------------------

typedef __attribute__((ext_vector_type(8))) short short8;
typedef __attribute__((ext_vector_type(4))) float floatx4;

#define NT_PER_B 28          // 3584/128

// workspace byte offsets
#define OFF_WP  0            // 9*2*512*128*2        = 2,359,296
#define OFF_A2  2359296      // 8*2*128*64*2         =   262,144
#define OFF_XP  2621440      // 64*58*8192*2         = 60,817,408
#define OFF_Y   63439872     // 896*4*16384*2        = 117,440,512
// total required ws: 180,880,384 bytes (~173 MB)

__device__ static inline void async16(const void* gptr, void* lptr) {
  __builtin_amdgcn_global_load_lds(
      (const __attribute__((address_space(1))) void*)gptr,
      (__attribute__((address_space(3))) void*)lptr,
      16, 0, 0);
}

__device__ static inline unsigned short f2bf(float x) {
  __hip_bfloat16 h = __float2bfloat16(x);
  return *reinterpret_cast<unsigned short*>(&h);
}

// ---------------- prep: x (NCHW f32) -> Xp[b*2+cg][h'58][khi16][w'64][klo8] bf16
__global__ void k_xprep(const float* __restrict__ x, __hip_bfloat16* __restrict__ Xp) {
  const int t = blockIdx.x * 256 + threadIdx.x;
  const int wq  = t & 63;
  const int khi = (t >> 6) & 15;
  const int t2  = t >> 10;                               // bc*58 + hp
  const int hp  = t2 % 58;
  const int bc  = t2 / 58;
  const int b   = bc >> 1;
  const int cin0 = ((bc & 1) << 7) + (khi << 3);
  const int h = hp - 1, w = wq - 1;
  unsigned short v[8];
  if ((unsigned)h < 56u && (unsigned)w < 56u) {
    const float* xp = x + ((size_t)(b * 256 + cin0) * 56 + h) * 56 + w;
#pragma unroll
    for (int j = 0; j < 8; ++j) v[j] = f2bf(xp[(size_t)j * 3136]);
  } else {
#pragma unroll
    for (int j = 0; j < 8; ++j) v[j] = 0;
  }
  uint4 pk;
  pk.x = (unsigned)v[0] | ((unsigned)v[1] << 16);
  pk.y = (unsigned)v[2] | ((unsigned)v[3] << 16);
  pk.z = (unsigned)v[4] | ((unsigned)v[5] << 16);
  pk.w = (unsigned)v[6] | ((unsigned)v[7] << 16);
  *(uint4*)(Xp + (size_t)t * 8) = pk;
}

// ---------------- prep: binary_w -> Wp[tap9][cg2][cmblk4][khalf2][cmh2][khi8][cml64][klo8]
__global__ void k_wprep(const float* __restrict__ bw, __hip_bfloat16* __restrict__ Wp) {
  const int idx = blockIdx.x * 256 + threadIdx.x;        // < 1,179,648 exact
  const int klo   = idx & 7;
  const int cml   = (idx >> 3) & 63;
  const int khi   = (idx >> 9) & 7;
  const int cmh   = (idx >> 12) & 1;
  const int khalf = (idx >> 13) & 1;
  const int cmblk = (idx >> 14) & 3;
  const int cg    = (idx >> 16) & 1;
  const int tap   = idx >> 17;                           // 0..8
  const int cm  = (cmblk << 7) + (cmh << 6) + cml;
  const int cin = (cg << 7) + (khalf << 6) + (khi << 3) + klo;
  Wp[idx] = __float2bfloat16(bw[(cm * 256 + cin) * 9 + tap]);
}

// ---------------- prep: fc_w -> A2[kblk8][mtile2][ch2][khi8][cl64][klo8]
__global__ void k_a2prep(const float* __restrict__ fw, __hip_bfloat16* __restrict__ A2) {
  const int idx = blockIdx.x * 256 + threadIdx.x;        // < 131,072 exact
  const int klo   = idx & 7;
  const int cl    = (idx >> 3) & 63;
  const int khi   = (idx >> 9) & 7;
  const int ch    = (idx >> 12) & 1;
  const int mtile = (idx >> 13) & 1;
  const int kblk  = idx >> 14;                           // 0..7
  const int cout = (mtile << 7) + (ch << 6) + cl;
  const int cm   = (kblk << 6) + (khi << 3) + klo;
  A2[idx] = __float2bfloat16(fw[cout * 512 + cm]);
}

// ---------------- conv1: Y[ntile][cmblk][khalf2][r2][khi8][w64][klo8] = relu(W*Xp)
// BK=64, 32KB LDS -> 5 blocks/CU. XCD-contiguous swizzle (xcd = id&7).
__global__ __launch_bounds__(256, 5) void k_conv1(
    const __hip_bfloat16* __restrict__ Xp, const __hip_bfloat16* __restrict__ Wp,
    __hip_bfloat16* __restrict__ Y) {
  __shared__ char lds[32768];                            // A[0,16K) B[16K,32K)
  const int tid  = threadIdx.x;
  const int lane = tid & 63;
  const int wv   = tid >> 6;
  const int wm   = wv >> 1, wn = wv & 1;
  const int l15  = lane & 15;
  const int quad = lane >> 4;
  const int id   = blockIdx.x;
  const int xcd  = id & 7;
  const int seq  = id >> 3;                              // 0..447
  const int cmblk = seq & 3;
  const int ntile = xcd * 112 + (seq >> 2);              // 0..895
  const int b  = ntile / NT_PER_B;
  const int h0 = (ntile % NT_PER_B) * 2;
  const char* WpB = (const char*)Wp;
  const char* XpB = (const char*)Xp;

  floatx4 acc[4][4];
#pragma unroll
  for (int i = 0; i < 4; i++)
#pragma unroll
    for (int j = 0; j < 4; j++) acc[i][j] = (floatx4){0.f, 0.f, 0.f, 0.f};

  for (int t = 0; t < 36; ++t) {
    const int tap   = t >> 2;
    const int cg    = (t >> 1) & 1;
    const int khalf = t & 1;
    const int kh = tap / 3, kw = tap - kh * 3;
    const size_t a_base = (size_t)((((tap * 2 + cg) * 4 + cmblk) * 2) + khalf) << 14;
    const size_t b_base = ((size_t)((b * 2 + cg) * 58 + (h0 + kh)) << 14) + kw * 16 + (khalf << 13);
    __syncthreads();                                     // prev compute done
#pragma unroll
    for (int c = 0; c < 4; ++c) {
      const int off = c * 4096 + tid * 16;
      async16(WpB + a_base + off, lds + off);
      const int row = off >> 13;                         // 0 or 1
      const int inner = off & 8191;
      async16(XpB + b_base + (size_t)row * 16384 + inner, lds + 16384 + off);
    }
    __syncthreads();                                     // staging visible
#pragma unroll
    for (int kk = 0; kk < 2; ++kk) {
      short8 af[4], bf[4];
#pragma unroll
      for (int mi = 0; mi < 4; ++mi) {
        const int m = wm * 64 + mi * 16 + l15;
        af[mi] = *(const short8*)(lds + (m >> 6) * 8192 + (kk * 4 + quad) * 1024 + (m & 63) * 16);
      }
#pragma unroll
      for (int ni = 0; ni < 4; ++ni) {
        const int n = wn * 64 + ni * 16 + l15;
        bf[ni] = *(const short8*)(lds + 16384 + (n >> 6) * 8192 + (kk * 4 + quad) * 1024 + (n & 63) * 16);
      }
#pragma unroll
      for (int mi = 0; mi < 4; ++mi)
#pragma unroll
        for (int ni = 0; ni < 4; ++ni)
          acc[mi][ni] = __builtin_amdgcn_mfma_f32_16x16x32_bf16(af[mi], bf[ni], acc[mi][ni], 0, 0, 0);
    }
  }

  // epilogue: relu -> bf16, chunk (ntile,cmblk) layout [khalf2][r2][khi8][w64][klo8]
  const size_t ybase = ((size_t)ntile * 4 + cmblk) * 16384;  // elems
#pragma unroll
  for (int mi = 0; mi < 4; ++mi) {
    const int cmL   = wm * 64 + mi * 16 + quad * 4;      // + reg r (0..3)
    const int khalf = (cmL >> 6) & 1;
    const int khi   = (cmL >> 3) & 7;
    const int klo0  = cmL & 7;                           // 0 or 4
#pragma unroll
    for (int ni = 0; ni < 4; ++ni) {
      const int n = wn * 64 + ni * 16 + l15;
      const int r = n >> 6, w = n & 63;
      floatx4 f = acc[mi][ni];
      unsigned lo = (unsigned)f2bf(fmaxf(f[0], 0.f)) | ((unsigned)f2bf(fmaxf(f[1], 0.f)) << 16);
      unsigned hi = (unsigned)f2bf(fmaxf(f[2], 0.f)) | ((unsigned)f2bf(fmaxf(f[3], 0.f)) << 16);
      uint2 pk = make_uint2(lo, hi);
      *(uint2*)((char*)Y + (ybase + (size_t)khalf * 8192 + r * 4096 + khi * 512 + w * 8 + klo0) * 2) = pk;
    }
  }
}

// ---------------- conv2: out = fc_w * Y + b, mask w<56, store NCHW f32
// BK=64, 32KB LDS -> 5 blocks/CU. Same-XCD rp range as conv1 for Y L2 hits.
__global__ __launch_bounds__(256, 5) void k_conv2(
    const __hip_bfloat16* __restrict__ Y, const __hip_bfloat16* __restrict__ A2,
    const float* __restrict__ fcb, float* __restrict__ out) {
  __shared__ char lds[32768];
  const int tid  = threadIdx.x;
  const int lane = tid & 63;
  const int wv   = tid >> 6;
  const int wm   = wv >> 1, wn = wv & 1;
  const int l15  = lane & 15;
  const int quad = lane >> 4;
  const int id   = blockIdx.x;
  const int xcd  = id & 7;
  const int seq  = id >> 3;                              // 0..223
  const int mtile = seq & 1;
  const int rp    = xcd * 112 + (seq >> 1);              // 0..895
  const char* A2B = (const char*)A2;
  const char* YB  = (const char*)Y;

  floatx4 acc[4][4];
#pragma unroll
  for (int i = 0; i < 4; i++)
#pragma unroll
    for (int j = 0; j < 4; j++) acc[i][j] = (floatx4){0.f, 0.f, 0.f, 0.f};

  for (int kb = 0; kb < 8; ++kb) {
    const size_t a_base = (size_t)(kb * 2 + mtile) << 14;
    const size_t b_base = ((size_t)(rp * 4 + (kb >> 1)) << 15) + ((size_t)(kb & 1) << 14);
    __syncthreads();
#pragma unroll
    for (int c = 0; c < 4; ++c) {
      const int off = c * 4096 + tid * 16;
      async16(A2B + a_base + off, lds + off);
      async16(YB + b_base + off, lds + 16384 + off);
    }
    __syncthreads();
#pragma unroll
    for (int kk = 0; kk < 2; ++kk) {
      short8 af[4], bf[4];
#pragma unroll
      for (int mi = 0; mi < 4; ++mi) {
        const int m = wm * 64 + mi * 16 + l15;
        af[mi] = *(const short8*)(lds + (m >> 6) * 8192 + (kk * 4 + quad) * 1024 + (m & 63) * 16);
      }
#pragma unroll
      for (int ni = 0; ni < 4; ++ni) {
        const int n = wn * 64 + ni * 16 + l15;
        bf[ni] = *(const short8*)(lds + 16384 + (n >> 6) * 8192 + (kk * 4 + quad) * 1024 + (n & 63) * 16);
      }
#pragma unroll
      for (int mi = 0; mi < 4; ++mi)
#pragma unroll
        for (int ni = 0; ni < 4; ++ni)
          acc[mi][ni] = __builtin_amdgcn_mfma_f32_16x16x32_bf16(af[mi], bf[ni], acc[mi][ni], 0, 0, 0);
    }
  }

  const int b   = rp / NT_PER_B;
  const int nb0 = (rp % NT_PER_B) * 128;
#pragma unroll
  for (int mi = 0; mi < 4; ++mi) {
    const int co = mtile * 128 + wm * 64 + mi * 16 + quad * 4;  // + reg r
#pragma unroll
    for (int ni = 0; ni < 4; ++ni) {
      const int n = wn * 64 + ni * 16 + l15;
      const int w = n & 63;
      if (w < 56) {
        const int nb = nb0 + n;
        const int h  = nb >> 6;
        floatx4 f = acc[mi][ni];
        const size_t base = (size_t)(b * 256 + co) * 3136 + h * 56 + w;
#pragma unroll
        for (int r = 0; r < 4; ++r)
          out[base + (size_t)r * 3136] = f[r] + fcb[co + r];
      }
    }
  }
}

extern "C" void kernel_launch(void* const* d_in, const int* in_sizes, int n_in,
                              void* d_out, int out_size, void* d_ws, size_t ws_size,
                              hipStream_t stream) {
  const float* x  = (const float*)d_in[0];
  const float* bw = (const float*)d_in[1];
  const float* fw = (const float*)d_in[2];
  const float* fb = (const float*)d_in[3];
  float* out = (float*)d_out;
  char* ws = (char*)d_ws;

  __hip_bfloat16* Wp = (__hip_bfloat16*)(ws + OFF_WP);
  __hip_bfloat16* A2 = (__hip_bfloat16*)(ws + OFF_A2);
  __hip_bfloat16* Xp = (__hip_bfloat16*)(ws + OFF_XP);
  __hip_bfloat16* Y  = (__hip_bfloat16*)(ws + OFF_Y);

  k_wprep<<<dim3(4608), dim3(256), 0, stream>>>(bw, Wp);
  k_a2prep<<<dim3(512), dim3(256), 0, stream>>>(fw, A2);
  k_xprep<<<dim3(14848), dim3(256), 0, stream>>>(x, Xp);
  k_conv1<<<dim3(3584), dim3(256), 0, stream>>>(Xp, Wp, Y);
  k_conv2<<<dim3(1792), dim3(256), 0, stream>>>(Y, A2, fb, out);
}